// Round 7
// baseline (241.715 us; speedup 1.0000x reference)
//
#include <hip/hip_runtime.h>
#include <hip/hip_bf16.h>

typedef __bf16 bf16_t;
typedef __bf16 bf16x4 __attribute__((ext_vector_type(4)));
typedef __bf16 bf16x8 __attribute__((ext_vector_type(8)));
typedef _Float16 f16_t;
typedef _Float16 f16x4 __attribute__((ext_vector_type(4)));
typedef _Float16 f16x8 __attribute__((ext_vector_type(8)));
typedef __fp16 hf2 __attribute__((ext_vector_type(2)));
typedef float f32x4 __attribute__((ext_vector_type(4)));

#define MFMA16(a, b, c)  __builtin_amdgcn_mfma_f32_16x16x32_bf16((a), (b), (c), 0, 0, 0)
#define MFMA32H(a, b, c) __builtin_amdgcn_mfma_f32_16x16x32_f16((a), (b), (c), 0, 0, 0)

// softmax scale: 1/sqrt(64) * log2(e), folded into Q projection (base-2 softmax)
#define QSCALE 0.18033688089869237f

typedef __attribute__((address_space(3))) void lds_void;
typedef const __attribute__((address_space(1))) void glob_void;
static __device__ __forceinline__ void gl_lds16(const void* g, void* l) {
    __builtin_amdgcn_global_load_lds((glob_void*)g, (lds_void*)l, 16, 0, 0);
}

// ---------------------------------------------------------------------------
// prep: (a) blocks 0..255: LDS-transpose Wq/Wk/Wv [H,D,F]f32 -> WT[n=h*64+f][d]bf16
//       (b) blocks 256..4351: cast inputs q/k/v f32->bf16 (+ Wo cast)
// ---------------------------------------------------------------------------
__global__ __launch_bounds__(256) void prep(
    const float* __restrict__ Wq, const float* __restrict__ Wk,
    const float* __restrict__ Wv, const float* __restrict__ Wo,
    const float* __restrict__ qin, const float* __restrict__ kin,
    const float* __restrict__ vin,
    bf16_t* __restrict__ WqT, bf16_t* __restrict__ WkT,
    bf16_t* __restrict__ WvT, bf16_t* __restrict__ WoT,
    bf16_t* __restrict__ qb, bf16_t* __restrict__ kb, bf16_t* __restrict__ vb)
{
    const int t = threadIdx.x;
    if (blockIdx.x < 256) {
        __shared__ float tile[64][65];
        const int h = blockIdx.x >> 4, d0 = (blockIdx.x & 15) << 6;
        const float* Ws[3] = {Wq, Wk, Wv};
        bf16_t* Wt[3] = {WqT, WkT, WvT};
        const int r = t >> 4, c4 = (t & 15) << 2;
        for (int s = 0; s < 3; ++s) {
            const float* W = Ws[s] + ((size_t)h << 16);
#pragma unroll
            for (int i = 0; i < 4; ++i) {
                float4 v = *(const float4*)&W[(size_t)(d0 + i * 16 + r) * 64 + c4];
                tile[i * 16 + r][c4 + 0] = v.x; tile[i * 16 + r][c4 + 1] = v.y;
                tile[i * 16 + r][c4 + 2] = v.z; tile[i * 16 + r][c4 + 3] = v.w;
            }
            __syncthreads();
#pragma unroll
            for (int i = 0; i < 4; ++i) {
                int f = i * 16 + r;
                bf16x4 o;
                o[0] = (bf16_t)tile[c4 + 0][f]; o[1] = (bf16_t)tile[c4 + 1][f];
                o[2] = (bf16_t)tile[c4 + 2][f]; o[3] = (bf16_t)tile[c4 + 3][f];
                *(bf16x4*)&Wt[s][(((size_t)(h << 6) + f) << 10) + d0 + c4] = o;
            }
            __syncthreads();
        }
    } else {
        size_t id = (size_t)(blockIdx.x - 256) * 256 + t;  // 0..1M-1, 4 elems each
        size_t e = id * 4;
        {
            float4 v = *(const float4*)&qin[e];
            bf16x4 o = {(bf16_t)v.x, (bf16_t)v.y, (bf16_t)v.z, (bf16_t)v.w};
            *(bf16x4*)&qb[e] = o;
        }
        {
            float4 v = *(const float4*)&kin[e];
            bf16x4 o = {(bf16_t)v.x, (bf16_t)v.y, (bf16_t)v.z, (bf16_t)v.w};
            *(bf16x4*)&kb[e] = o;
        }
        {
            float4 v = *(const float4*)&vin[e];
            bf16x4 o = {(bf16_t)v.x, (bf16_t)v.y, (bf16_t)v.z, (bf16_t)v.w};
            *(bf16x4*)&vb[e] = o;
        }
        if (id < 262144) {
            float4 v = *(const float4*)&Wo[e];
            bf16x4 o = {(bf16_t)v.x, (bf16_t)v.y, (bf16_t)v.z, (bf16_t)v.w};
            *(bf16x4*)&WoT[e] = o;
        }
    }
}

// ---------------------------------------------------------------------------
// GEMM core: C 128x64 = A[128rows][K] * B[64rows][K]^T, BK=64, 256 thr
// (4 waves 2x2, wave-tile 64x32). global_load_lds width 16 staging into an
// XOR-SWIZZLED LDS layout: element (row, col8) -> row*64 + (col8^(row&7))*8.
// Staging keeps the wave-uniform-base DMA (only the per-lane SOURCE column is
// permuted, coalescing preserved); fragment ds_read_b128 banks then spread
// over all 32 banks (only free 2-way m/m+8 aliasing) instead of 16-way.
// ---------------------------------------------------------------------------
static __device__ __forceinline__ void gemm_core(
    const bf16_t* __restrict__ A, const bf16_t* __restrict__ B,
    int m0, int n0, int K, bf16_t* As, bf16_t* Bs, f32x4 acc[4][2])
{
    const int tid = threadIdx.x, lane = tid & 63, w = tid >> 6;
    const int m = lane & 15, quad = lane >> 4;
    const int wm = (w >> 1) * 64, wn = (w & 1) * 32;
    const int lrow = lane >> 3;
    // swizzled source column for this lane's fixed LDS slot
    const int lcol = (((lane & 7) ^ (lrow & 7)) << 3);

    for (int kt = 0; kt < K; kt += 64) {
#pragma unroll
        for (int i = 0; i < 4; ++i) {   // A: 16 chunks of 8 rows
            int chunk = i * 4 + w;
            gl_lds16(A + (size_t)(m0 + chunk * 8 + lrow) * K + kt + lcol, As + chunk * 512);
        }
#pragma unroll
        for (int i = 0; i < 2; ++i) {   // B: 8 chunks
            int chunk = i * 4 + w;
            gl_lds16(B + (size_t)(n0 + chunk * 8 + lrow) * K + kt + lcol, Bs + chunk * 512);
        }
        __syncthreads();
#pragma unroll
        for (int kc = 0; kc < 2; ++kc) {
            bf16x8 af[4], bfr[2];
#pragma unroll
            for (int x = 0; x < 4; ++x) {
                int row = wm + x * 16 + m;
                af[x] = *(const bf16x8*)&As[row * 64 + (((kc * 4 + quad) ^ (m & 7)) << 3)];
            }
#pragma unroll
            for (int x = 0; x < 2; ++x) {
                int row = wn + x * 16 + m;
                bfr[x] = *(const bf16x8*)&Bs[row * 64 + (((kc * 4 + quad) ^ (m & 7)) << 3)];
            }
#pragma unroll
            for (int mt = 0; mt < 4; ++mt)
#pragma unroll
                for (int nt = 0; nt < 2; ++nt)
                    acc[mt][nt] = MFMA16(af[mt], bfr[nt], acc[mt][nt]);
        }
        __syncthreads();
    }
}

// proj GEMM: 128x64 tiles, grid (16 n, 32 m, 3 z) = 1536 blocks = 6/CU.
// z=0 -> Qs=(x*Wq+bq)*QSCALE bf16; z=1 -> Ks bf16; z=2 -> Vt (transposed) f16
__global__ __launch_bounds__(256, 6) void gemm_proj(
    const bf16_t* __restrict__ qb, const bf16_t* __restrict__ kb,
    const bf16_t* __restrict__ vb, const bf16_t* __restrict__ WT,
    const float* __restrict__ bq, const float* __restrict__ bk,
    const float* __restrict__ bv,
    bf16_t* __restrict__ Qs, bf16_t* __restrict__ Ksb, f16_t* __restrict__ Vt)
{
    __shared__ alignas(16) bf16_t As[128 * 64], Bs[64 * 64];
    const int z = blockIdx.z;
    const bf16_t* A = (z == 0) ? qb : (z == 1) ? kb : vb;
    const bf16_t* B = WT + (size_t)z * (1024 * 1024);
    const float* bias = (z == 0) ? bq : (z == 1) ? bk : bv;
    const int m0 = blockIdx.y * 128, n0 = blockIdx.x * 64;

    f32x4 zero = {0.f, 0.f, 0.f, 0.f};
    f32x4 acc[4][2];
#pragma unroll
    for (int i = 0; i < 4; ++i) { acc[i][0] = zero; acc[i][1] = zero; }

    gemm_core(A, B, m0, n0, 1024, As, Bs, acc);

    const int lane = threadIdx.x & 63, w = threadIdx.x >> 6;
    const int m = lane & 15, quad = lane >> 4;
    const int wm = (w >> 1) * 64, wn = (w & 1) * 32;

    if (z == 2) {
        // transposed f16 store: Vt[b][col][s], 4 consecutive s per lane -> 8B packed
#pragma unroll
        for (int mt = 0; mt < 4; ++mt)
#pragma unroll
            for (int nt = 0; nt < 2; ++nt) {
                int col = n0 + wn + nt * 16 + m;
                float bb = bias[col];
                int row0 = m0 + wm + mt * 16 + quad * 4;
                int bi = row0 >> 11, s = row0 & 2047;
                f16x4 p;
#pragma unroll
                for (int r = 0; r < 4; ++r) p[r] = (f16_t)(acc[mt][nt][r] + bb);
                *(f16x4*)&Vt[((size_t)bi * 1024 + col) * 2048 + s] = p;
            }
    } else {
        bf16_t* out = z ? Ksb : Qs;
        float sc = z ? 1.0f : QSCALE;
#pragma unroll
        for (int mt = 0; mt < 4; ++mt)
#pragma unroll
            for (int nt = 0; nt < 2; ++nt) {
                int col = n0 + wn + nt * 16 + m;
                float bb = bias[col];
#pragma unroll
                for (int r = 0; r < 4; ++r) {
                    int row = m0 + wm + mt * 16 + quad * 4 + r;
                    out[(size_t)row * 1024 + col] = (bf16_t)((acc[mt][nt][r] + bb) * sc);
                }
            }
    }
}

// out GEMM: d_out = Os * WoT^T + bo, f32 out. 128x64 tiles -> 512 blocks.
__global__ __launch_bounds__(256) void gemm_out(
    const bf16_t* __restrict__ Aos, const bf16_t* __restrict__ WoT,
    const float* __restrict__ bo, float* __restrict__ out)
{
    __shared__ alignas(16) bf16_t As[128 * 64], Bs[64 * 64];
    const int m0 = blockIdx.y * 128, n0 = blockIdx.x * 64;

    f32x4 zero = {0.f, 0.f, 0.f, 0.f};
    f32x4 acc[4][2];
#pragma unroll
    for (int i = 0; i < 4; ++i) { acc[i][0] = zero; acc[i][1] = zero; }

    gemm_core(Aos, WoT, m0, n0, 1024, As, Bs, acc);

    const int lane = threadIdx.x & 63, w = threadIdx.x >> 6;
    const int m = lane & 15, quad = lane >> 4;
    const int wm = (w >> 1) * 64, wn = (w & 1) * 32;
#pragma unroll
    for (int mt = 0; mt < 4; ++mt)
#pragma unroll
        for (int nt = 0; nt < 2; ++nt) {
            int col = n0 + wn + nt * 16 + m;
            float bb = bo[col];
#pragma unroll
            for (int r = 0; r < 4; ++r) {
                int row = m0 + wm + mt * 16 + quad * 4 + r;
                out[(size_t)row * 1024 + col] = acc[mt][nt][r] + bb;
            }
        }
}

// ---------------------------------------------------------------------------
// attn v5 (unchanged from R6): Sᵀ = K·Qᵀ, P in registers, base-2 softmax,
// 32 q/wave, 2-way K-split (1024 blocks = 4/CU), PV via f16 16x16x32 MFMA
// (P regs form the x32 A-frag under pi(quad*8+j)=(j>=4)*16+quad*4+(j&3)).
// Partial O (f16) + row-sums l (f32); combine kernel merges.
// ---------------------------------------------------------------------------
__global__ __launch_bounds__(256, 4) void attn5(
    const bf16_t* __restrict__ Qb, const bf16_t* __restrict__ Kb,
    const f16_t* __restrict__ Vt, f16_t* __restrict__ Op, float* __restrict__ Ls)
{
    __shared__ alignas(16) bf16_t Ks[2][32][72];   // [key][feat]
    __shared__ alignas(16) f16_t  Vts[2][64][40];  // [feat][key]

    const int tid = threadIdx.x, lane = tid & 63, w = tid >> 6;
    const int m = lane & 15, quad = lane >> 4;
    const int bh = blockIdx.x, b = bh >> 4, h = bh & 15;
    const int q0 = blockIdx.y * 128;
    const int ks = blockIdx.z;             // K-split half
    const int kt0 = ks << 10;
    const size_t base = (size_t)b * 2048 * 1024 + h * 64;     // token-major Q/K
    const size_t vbase = ((size_t)b * 1024 + h * 64) * 2048;  // Vt [f][s]

    // persistent Q B-fragments: 32 q/wave; lane&15 = q, k = quad*8+j
    bf16x8 aq[2][2];
#pragma unroll
    for (int qt = 0; qt < 2; ++qt) {
        const bf16_t* qp = Qb + base + (size_t)(q0 + w * 32 + qt * 16 + m) * 1024;
        aq[qt][0] = *(const bf16x8*)(qp + quad * 8);
        aq[qt][1] = *(const bf16x8*)(qp + 32 + quad * 8);
    }
    f16x8 ones8;
#pragma unroll
    for (int j = 0; j < 8; ++j) ones8[j] = (f16_t)1.0f;

    f32x4 zero = {0.f, 0.f, 0.f, 0.f};
    f32x4 acc[2][5];
#pragma unroll
    for (int qt = 0; qt < 2; ++qt)
#pragma unroll
        for (int i = 0; i < 5; ++i) acc[qt][i] = zero;

    const int kkey = tid >> 3, kfo = (tid & 7) * 8;  // K tile 32 keys x 64 f
    const int vf = tid >> 2, vko = (tid & 3) * 8;    // V tile 64 f x 32 keys

    bf16x8 rk = *(const bf16x8*)(Kb + base + (size_t)(kt0 + kkey) * 1024 + kfo);
    f16x8  rv = *(const f16x8*)(Vt + vbase + (size_t)vf * 2048 + kt0 + vko);

    int buf = 0;
    for (int kt = kt0; kt < kt0 + 1024; kt += 32) {
        *(bf16x8*)&Ks[buf][kkey][kfo] = rk;
        *(f16x8*)&Vts[buf][vf][vko] = rv;
        __syncthreads();
        if (kt + 32 < kt0 + 1024) {
            rk = *(const bf16x8*)(Kb + base + (size_t)(kt + 32 + kkey) * 1024 + kfo);
            rv = *(const f16x8*)(Vt + vbase + (size_t)vf * 2048 + kt + 32 + vko);
        }

        // Sᵀ[key][q]: A = K frags (lane&15 = key), B = Q frags (lane&15 = q)
        f32x4 s[2][2];  // [kl][qt]
#pragma unroll
        for (int kl = 0; kl < 2; ++kl) {
            bf16x8 a0 = *(const bf16x8*)&Ks[buf][kl * 16 + m][quad * 8];
            bf16x8 a1 = *(const bf16x8*)&Ks[buf][kl * 16 + m][32 + quad * 8];
#pragma unroll
            for (int qt = 0; qt < 2; ++qt) {
                f32x4 t = MFMA16(a0, aq[qt][0], zero);
                s[kl][qt] = MFMA16(a1, aq[qt][1], t);
            }
        }

        // p = 2^s; lane holds P[q=lane&15][key=kl*16+quad*4+r]; the f16x8
        // [p_kl0 | p_kl1] is an x32 f16 A-frag under pi (see header comment)
        f16x8 p[2];  // [qt]
#pragma unroll
        for (int qt = 0; qt < 2; ++qt)
#pragma unroll
            for (int kl = 0; kl < 2; ++kl) {
                hf2 lo = __builtin_amdgcn_cvt_pkrtz(
                    __builtin_amdgcn_exp2f(s[kl][qt][0]),
                    __builtin_amdgcn_exp2f(s[kl][qt][1]));
                hf2 hi = __builtin_amdgcn_cvt_pkrtz(
                    __builtin_amdgcn_exp2f(s[kl][qt][2]),
                    __builtin_amdgcn_exp2f(s[kl][qt][3]));
                p[qt][kl * 4 + 0] = lo[0]; p[qt][kl * 4 + 1] = lo[1];
                p[qt][kl * 4 + 2] = hi[0]; p[qt][kl * 4 + 3] = hi[1];
            }

        // O[q][f] += P V via x32 f16; B-frag under pi = two b64 reads
#pragma unroll
        for (int ft = 0; ft < 4; ++ft) {
            f16x4 lo = *(const f16x4*)&Vts[buf][ft * 16 + m][quad * 4];
            f16x4 hi = *(const f16x4*)&Vts[buf][ft * 16 + m][16 + quad * 4];
            f16x8 bv;
#pragma unroll
            for (int j = 0; j < 4; ++j) { bv[j] = lo[j]; bv[4 + j] = hi[j]; }
#pragma unroll
            for (int qt = 0; qt < 2; ++qt)
                acc[qt][ft] = MFMA32H(p[qt], bv, acc[qt][ft]);
        }
#pragma unroll
        for (int qt = 0; qt < 2; ++qt)
            acc[qt][4] = MFMA32H(p[qt], ones8, acc[qt][4]);  // row sums

        buf ^= 1;
    }

    // store partials (no normalize): Op[ks][grow][h*64+f] f16, Ls[ks][grow][h] f32
#pragma unroll
    for (int qt = 0; qt < 2; ++qt)
#pragma unroll
        for (int r = 0; r < 4; ++r) {
            int grow = (b << 11) + q0 + w * 32 + qt * 16 + quad * 4 + r;
            f16_t* op = Op + (((size_t)ks << 12) + grow) * 1024 + (h << 6);
#pragma unroll
            for (int ft = 0; ft < 4; ++ft)
                op[ft * 16 + m] = (f16_t)(acc[qt][ft][r]);
            if (m == 0)
                Ls[((((size_t)ks << 12) + grow) << 4) + h] = acc[qt][4][r];
        }
}

// combine: Os = (Op0 + Op1) / (l0 + l1), bf16 out
__global__ __launch_bounds__(256) void combine(
    const f16_t* __restrict__ Op, const float* __restrict__ Ls,
    bf16_t* __restrict__ Os)
{
    size_t idx = ((size_t)blockIdx.x * 256 + threadIdx.x) * 8;
    int row = (int)(idx >> 10), h = (int)((idx & 1023) >> 6);
    f16x8 a = *(const f16x8*)&Op[idx];
    f16x8 c = *(const f16x8*)&Op[(size_t)4096 * 1024 + idx];
    float l = Ls[row * 16 + h] + Ls[4096 * 16 + row * 16 + h];
    float inv = __builtin_amdgcn_rcpf(l);
    bf16x8 o;
#pragma unroll
    for (int i = 0; i < 8; ++i)
        o[i] = (bf16_t)(((float)a[i] + (float)c[i]) * inv);
    *(bf16x8*)&Os[idx] = o;
}

// ---------------------------------------------------------------------------
extern "C" void kernel_launch(void* const* d_in, const int* in_sizes, int n_in,
                              void* d_out, int out_size, void* d_ws, size_t ws_size,
                              hipStream_t stream)
{
    const float* queries = (const float*)d_in[0];
    const float* keys    = (const float*)d_in[1];
    const float* values  = (const float*)d_in[2];
    const float* Wq = (const float*)d_in[3];
    const float* Wk = (const float*)d_in[4];
    const float* Wv = (const float*)d_in[5];
    const float* bq = (const float*)d_in[6];
    const float* bk = (const float*)d_in[7];
    const float* bv = (const float*)d_in[8];
    const float* Wo = (const float*)d_in[9];
    const float* bo = (const float*)d_in[10];

    char* ws = (char*)d_ws;
    const size_t MB = 1024 * 1024;
    bf16_t* WqT = (bf16_t*)(ws + 0 * MB);   // 2MB each, contiguous (base + z*1M elems)
    bf16_t* WkT = (bf16_t*)(ws + 2 * MB);
    bf16_t* WvT = (bf16_t*)(ws + 4 * MB);
    bf16_t* WoT = (bf16_t*)(ws + 6 * MB);
    bf16_t* qb  = (bf16_t*)(ws + 8 * MB);   // 8MB each: bf16-cast inputs
    bf16_t* kb  = (bf16_t*)(ws + 16 * MB);
    bf16_t* vb  = (bf16_t*)(ws + 24 * MB);
    f16_t*  Vt  = (f16_t*)(ws + 32 * MB);   // 8MB, [b][h*64+f][s] f16
    f16_t*  Op  = (f16_t*)(ws + 40 * MB);   // 16MB, f16 [2][4096][1024] partial O
    float*  Lsp = (float*)(ws + 56 * MB);   // 512KB, f32 [2][4096][16] partial l
    // scratch reuse: Q/K projections live in d_out (16MB) until the final GEMM;
    // combined attention output overwrites qb (no longer needed).
    bf16_t* Qs  = (bf16_t*)d_out;
    bf16_t* Ksb = (bf16_t*)((char*)d_out + 8 * MB);
    bf16_t* Os  = qb;
    (void)WkT; (void)WvT;

    prep<<<4352, 256, 0, stream>>>(Wq, Wk, Wv, Wo, queries, keys, values,
                                   WqT, WkT, WvT, WoT, qb, kb, vb);

    gemm_proj<<<dim3(16, 32, 3), 256, 0, stream>>>(qb, kb, vb, WqT, bq, bk, bv,
                                                   Qs, Ksb, Vt);

    attn5<<<dim3(32, 16, 2), 256, 0, stream>>>(Qs, Ksb, Vt, Op, Lsp);

    combine<<<2048, 256, 0, stream>>>(Op, Lsp, Os);

    gemm_out<<<dim3(16, 32), 256, 0, stream>>>(Os, WoT, bo, (float*)d_out);
}

// Round 8
// 225.693 us; speedup vs baseline: 1.0710x; 1.0710x over previous
//
#include <hip/hip_runtime.h>
#include <hip/hip_bf16.h>

typedef __bf16 bf16_t;
typedef __bf16 bf16x4 __attribute__((ext_vector_type(4)));
typedef __bf16 bf16x8 __attribute__((ext_vector_type(8)));
typedef _Float16 f16_t;
typedef _Float16 f16x4 __attribute__((ext_vector_type(4)));
typedef _Float16 f16x8 __attribute__((ext_vector_type(8)));
typedef __fp16 hf2 __attribute__((ext_vector_type(2)));
typedef float f32x4 __attribute__((ext_vector_type(4)));

#define MFMA16(a, b, c)  __builtin_amdgcn_mfma_f32_16x16x32_bf16((a), (b), (c), 0, 0, 0)
#define MFMA32H(a, b, c) __builtin_amdgcn_mfma_f32_16x16x32_f16((a), (b), (c), 0, 0, 0)

// softmax scale: 1/sqrt(64) * log2(e), folded into Q projection (base-2 softmax)
#define QSCALE 0.18033688089869237f

typedef __attribute__((address_space(3))) void lds_void;
typedef const __attribute__((address_space(1))) void glob_void;
static __device__ __forceinline__ void gl_lds16(const void* g, void* l) {
    __builtin_amdgcn_global_load_lds((glob_void*)g, (lds_void*)l, 16, 0, 0);
}

// ---------------------------------------------------------------------------
// prep: (a) blocks 0..255: LDS-transpose Wq/Wk/Wv [H,D,F]f32 -> WT[n=h*64+f][d]bf16
//       (b) blocks 256..4351: cast inputs q/k/v f32->bf16 (+ Wo cast)
// ---------------------------------------------------------------------------
__global__ __launch_bounds__(256) void prep(
    const float* __restrict__ Wq, const float* __restrict__ Wk,
    const float* __restrict__ Wv, const float* __restrict__ Wo,
    const float* __restrict__ qin, const float* __restrict__ kin,
    const float* __restrict__ vin,
    bf16_t* __restrict__ WqT, bf16_t* __restrict__ WkT,
    bf16_t* __restrict__ WvT, bf16_t* __restrict__ WoT,
    bf16_t* __restrict__ qb, bf16_t* __restrict__ kb, bf16_t* __restrict__ vb)
{
    const int t = threadIdx.x;
    if (blockIdx.x < 256) {
        __shared__ float tile[64][65];
        const int h = blockIdx.x >> 4, d0 = (blockIdx.x & 15) << 6;
        const float* Ws[3] = {Wq, Wk, Wv};
        bf16_t* Wt[3] = {WqT, WkT, WvT};
        const int r = t >> 4, c4 = (t & 15) << 2;
        for (int s = 0; s < 3; ++s) {
            const float* W = Ws[s] + ((size_t)h << 16);
#pragma unroll
            for (int i = 0; i < 4; ++i) {
                float4 v = *(const float4*)&W[(size_t)(d0 + i * 16 + r) * 64 + c4];
                tile[i * 16 + r][c4 + 0] = v.x; tile[i * 16 + r][c4 + 1] = v.y;
                tile[i * 16 + r][c4 + 2] = v.z; tile[i * 16 + r][c4 + 3] = v.w;
            }
            __syncthreads();
#pragma unroll
            for (int i = 0; i < 4; ++i) {
                int f = i * 16 + r;
                bf16x4 o;
                o[0] = (bf16_t)tile[c4 + 0][f]; o[1] = (bf16_t)tile[c4 + 1][f];
                o[2] = (bf16_t)tile[c4 + 2][f]; o[3] = (bf16_t)tile[c4 + 3][f];
                *(bf16x4*)&Wt[s][(((size_t)(h << 6) + f) << 10) + d0 + c4] = o;
            }
            __syncthreads();
        }
    } else {
        size_t id = (size_t)(blockIdx.x - 256) * 256 + t;  // 0..1M-1, 4 elems each
        size_t e = id * 4;
        {
            float4 v = *(const float4*)&qin[e];
            bf16x4 o = {(bf16_t)v.x, (bf16_t)v.y, (bf16_t)v.z, (bf16_t)v.w};
            *(bf16x4*)&qb[e] = o;
        }
        {
            float4 v = *(const float4*)&kin[e];
            bf16x4 o = {(bf16_t)v.x, (bf16_t)v.y, (bf16_t)v.z, (bf16_t)v.w};
            *(bf16x4*)&kb[e] = o;
        }
        {
            float4 v = *(const float4*)&vin[e];
            bf16x4 o = {(bf16_t)v.x, (bf16_t)v.y, (bf16_t)v.z, (bf16_t)v.w};
            *(bf16x4*)&vb[e] = o;
        }
        if (id < 262144) {
            float4 v = *(const float4*)&Wo[e];
            bf16x4 o = {(bf16_t)v.x, (bf16_t)v.y, (bf16_t)v.z, (bf16_t)v.w};
            *(bf16x4*)&WoT[e] = o;
        }
    }
}

// ---------------------------------------------------------------------------
// 128x128 GEMM core (R6 tile + R7 XOR swizzle): BK=64, 256 thr, 4 waves 2x2
// of 64x64. LDS element (row, col8) -> row*64 + (col8^(row&7))*8: staging
// keeps wave-uniform-base DMA (per-lane SOURCE column permuted, coalescing
// kept); fragment ds_read_b128 spreads over all 32 banks (conflicts = 0,
// verified R7).
// ---------------------------------------------------------------------------
static __device__ __forceinline__ void gemm_core128(
    const bf16_t* __restrict__ A, const bf16_t* __restrict__ B,
    int m0, int n0, bf16_t* As, bf16_t* Bs, f32x4 acc[4][4])
{
    const int tid = threadIdx.x, lane = tid & 63, w = tid >> 6;
    const int m = lane & 15, quad = lane >> 4;
    const int wm = (w >> 1) * 64, wn = (w & 1) * 64;
    const int lrow = lane >> 3;
    const int lcol = (((lane & 7) ^ (lrow & 7)) << 3);  // swizzled source col

    for (int kt = 0; kt < 1024; kt += 64) {
#pragma unroll
        for (int i = 0; i < 4; ++i) {
            int chunk = i * 4 + w;
            int row = chunk * 8 + lrow;
            gl_lds16(A + (size_t)(m0 + row) * 1024 + kt + lcol, As + chunk * 512);
            gl_lds16(B + (size_t)(n0 + row) * 1024 + kt + lcol, Bs + chunk * 512);
        }
        __syncthreads();
#pragma unroll
        for (int kc = 0; kc < 2; ++kc) {
            bf16x8 af[4], bfr[4];
#pragma unroll
            for (int x = 0; x < 4; ++x) {
                int ra = wm + x * 16 + m, rb = wn + x * 16 + m;
                int co = ((kc * 4 + quad) ^ (m & 7)) << 3;
                af[x]  = *(const bf16x8*)&As[ra * 64 + co];
                bfr[x] = *(const bf16x8*)&Bs[rb * 64 + co];
            }
#pragma unroll
            for (int mt = 0; mt < 4; ++mt)
#pragma unroll
                for (int nt = 0; nt < 4; ++nt)
                    acc[mt][nt] = MFMA16(af[mt], bfr[nt], acc[mt][nt]);
        }
        __syncthreads();
    }
}

// proj GEMM: 128x128 tiles, 768 blocks 1-D, id = z*256 + n*32 + m so all 8
// n-blocks of a (z, m-stripe) share id%8 -> same XCD -> A-stripe L2 reuse.
// z=0 -> Qs=(x*Wq+bq)*QSCALE bf16; z=1 -> Ks bf16; z=2 -> Vt (transposed) f16
__global__ __launch_bounds__(256) void gemm_proj(
    const bf16_t* __restrict__ qb, const bf16_t* __restrict__ kb,
    const bf16_t* __restrict__ vb, const bf16_t* __restrict__ WT,
    const float* __restrict__ bq, const float* __restrict__ bk,
    const float* __restrict__ bv,
    bf16_t* __restrict__ Qs, bf16_t* __restrict__ Ksb, f16_t* __restrict__ Vt)
{
    __shared__ alignas(16) bf16_t As[8192], Bs[8192];
    const int id = blockIdx.x;
    const int z = id >> 8, rem = id & 255;
    const int n0 = (rem >> 5) * 128, m0 = (rem & 31) * 128;
    const bf16_t* A = (z == 0) ? qb : (z == 1) ? kb : vb;
    const bf16_t* B = WT + (size_t)z * (1024 * 1024);
    const float* bias = (z == 0) ? bq : (z == 1) ? bk : bv;

    f32x4 zero = {0.f, 0.f, 0.f, 0.f};
    f32x4 acc[4][4];
#pragma unroll
    for (int i = 0; i < 4; ++i)
#pragma unroll
        for (int j = 0; j < 4; ++j) acc[i][j] = zero;

    gemm_core128(A, B, m0, n0, As, Bs, acc);

    const int lane = threadIdx.x & 63, w = threadIdx.x >> 6;
    const int m = lane & 15, quad = lane >> 4;
    const int wm = (w >> 1) * 64, wn = (w & 1) * 64;

    if (z == 2) {
        // transposed f16 store: Vt[b][col][s], 4 consecutive s per lane -> 8B packed
#pragma unroll
        for (int mt = 0; mt < 4; ++mt)
#pragma unroll
            for (int nt = 0; nt < 4; ++nt) {
                int col = n0 + wn + nt * 16 + m;
                float bb = bias[col];
                int row0 = m0 + wm + mt * 16 + quad * 4;
                int bi = row0 >> 11, s = row0 & 2047;
                f16x4 p;
#pragma unroll
                for (int r = 0; r < 4; ++r) p[r] = (f16_t)(acc[mt][nt][r] + bb);
                *(f16x4*)&Vt[((size_t)bi * 1024 + col) * 2048 + s] = p;
            }
    } else {
        bf16_t* out = z ? Ksb : Qs;
        float sc = z ? 1.0f : QSCALE;
#pragma unroll
        for (int mt = 0; mt < 4; ++mt)
#pragma unroll
            for (int nt = 0; nt < 4; ++nt) {
                int col = n0 + wn + nt * 16 + m;
                float bb = bias[col];
#pragma unroll
                for (int r = 0; r < 4; ++r) {
                    int row = m0 + wm + mt * 16 + quad * 4 + r;
                    out[(size_t)row * 1024 + col] = (bf16_t)((acc[mt][nt][r] + bb) * sc);
                }
            }
    }
}

// out GEMM: d_out = Os * WoT^T + bo, f32 out. 128x64 tiles, 512 blocks 1-D,
// id = n*32 + m (same-stripe blocks share XCD). Swizzled LDS core.
__global__ __launch_bounds__(256) void gemm_out(
    const bf16_t* __restrict__ Aos, const bf16_t* __restrict__ WoT,
    const float* __restrict__ bo, float* __restrict__ out)
{
    __shared__ alignas(16) bf16_t As[128 * 64], Bs[64 * 64];
    const int tid = threadIdx.x, lane = tid & 63, w = tid >> 6;
    const int m = lane & 15, quad = lane >> 4;
    const int wm = (w >> 1) * 64, wn = (w & 1) * 32;
    const int id = blockIdx.x;
    const int m0 = (id & 31) * 128, n0 = (id >> 5) * 64;
    const int lrow = lane >> 3;
    const int lcol = (((lane & 7) ^ (lrow & 7)) << 3);

    f32x4 zero = {0.f, 0.f, 0.f, 0.f};
    f32x4 acc[4][2];
#pragma unroll
    for (int i = 0; i < 4; ++i) { acc[i][0] = zero; acc[i][1] = zero; }

    for (int kt = 0; kt < 1024; kt += 64) {
#pragma unroll
        for (int i = 0; i < 4; ++i) {
            int chunk = i * 4 + w;
            gl_lds16(Aos + (size_t)(m0 + chunk * 8 + lrow) * 1024 + kt + lcol, As + chunk * 512);
        }
#pragma unroll
        for (int i = 0; i < 2; ++i) {
            int chunk = i * 4 + w;
            gl_lds16(WoT + (size_t)(n0 + chunk * 8 + lrow) * 1024 + kt + lcol, Bs + chunk * 512);
        }
        __syncthreads();
#pragma unroll
        for (int kc = 0; kc < 2; ++kc) {
            bf16x8 af[4], bfr[2];
#pragma unroll
            for (int x = 0; x < 4; ++x) {
                int row = wm + x * 16 + m;
                af[x] = *(const bf16x8*)&As[row * 64 + (((kc * 4 + quad) ^ (m & 7)) << 3)];
            }
#pragma unroll
            for (int x = 0; x < 2; ++x) {
                int row = wn + x * 16 + m;
                bfr[x] = *(const bf16x8*)&Bs[row * 64 + (((kc * 4 + quad) ^ (m & 7)) << 3)];
            }
#pragma unroll
            for (int mt = 0; mt < 4; ++mt)
#pragma unroll
                for (int nt = 0; nt < 2; ++nt)
                    acc[mt][nt] = MFMA16(af[mt], bfr[nt], acc[mt][nt]);
        }
        __syncthreads();
    }

#pragma unroll
    for (int mt = 0; mt < 4; ++mt)
#pragma unroll
        for (int nt = 0; nt < 2; ++nt) {
            int col = n0 + wn + nt * 16 + m;
            float bb = bo[col];
#pragma unroll
            for (int r = 0; r < 4; ++r) {
                int row = m0 + wm + mt * 16 + quad * 4 + r;
                out[(size_t)row * 1024 + col] = acc[mt][nt][r] + bb;
            }
        }
}

// ---------------------------------------------------------------------------
// attn v5 (unchanged): Sᵀ = K·Qᵀ, P in registers, base-2 softmax, 32 q/wave,
// 2-way K-split (1024 blocks = 4/CU), PV via f16 16x16x32 MFMA.
// ---------------------------------------------------------------------------
__global__ __launch_bounds__(256, 4) void attn5(
    const bf16_t* __restrict__ Qb, const bf16_t* __restrict__ Kb,
    const f16_t* __restrict__ Vt, f16_t* __restrict__ Op, float* __restrict__ Ls)
{
    __shared__ alignas(16) bf16_t Ks[2][32][72];   // [key][feat]
    __shared__ alignas(16) f16_t  Vts[2][64][40];  // [feat][key]

    const int tid = threadIdx.x, lane = tid & 63, w = tid >> 6;
    const int m = lane & 15, quad = lane >> 4;
    const int bh = blockIdx.x, b = bh >> 4, h = bh & 15;
    const int q0 = blockIdx.y * 128;
    const int ks = blockIdx.z;             // K-split half
    const int kt0 = ks << 10;
    const size_t base = (size_t)b * 2048 * 1024 + h * 64;     // token-major Q/K
    const size_t vbase = ((size_t)b * 1024 + h * 64) * 2048;  // Vt [f][s]

    bf16x8 aq[2][2];
#pragma unroll
    for (int qt = 0; qt < 2; ++qt) {
        const bf16_t* qp = Qb + base + (size_t)(q0 + w * 32 + qt * 16 + m) * 1024;
        aq[qt][0] = *(const bf16x8*)(qp + quad * 8);
        aq[qt][1] = *(const bf16x8*)(qp + 32 + quad * 8);
    }
    f16x8 ones8;
#pragma unroll
    for (int j = 0; j < 8; ++j) ones8[j] = (f16_t)1.0f;

    f32x4 zero = {0.f, 0.f, 0.f, 0.f};
    f32x4 acc[2][5];
#pragma unroll
    for (int qt = 0; qt < 2; ++qt)
#pragma unroll
        for (int i = 0; i < 5; ++i) acc[qt][i] = zero;

    const int kkey = tid >> 3, kfo = (tid & 7) * 8;  // K tile 32 keys x 64 f
    const int vf = tid >> 2, vko = (tid & 3) * 8;    // V tile 64 f x 32 keys

    bf16x8 rk = *(const bf16x8*)(Kb + base + (size_t)(kt0 + kkey) * 1024 + kfo);
    f16x8  rv = *(const f16x8*)(Vt + vbase + (size_t)vf * 2048 + kt0 + vko);

    int buf = 0;
    for (int kt = kt0; kt < kt0 + 1024; kt += 32) {
        *(bf16x8*)&Ks[buf][kkey][kfo] = rk;
        *(f16x8*)&Vts[buf][vf][vko] = rv;
        __syncthreads();
        if (kt + 32 < kt0 + 1024) {
            rk = *(const bf16x8*)(Kb + base + (size_t)(kt + 32 + kkey) * 1024 + kfo);
            rv = *(const f16x8*)(Vt + vbase + (size_t)vf * 2048 + kt + 32 + vko);
        }

        // Sᵀ[key][q]: A = K frags (lane&15 = key), B = Q frags (lane&15 = q)
        f32x4 s[2][2];  // [kl][qt]
#pragma unroll
        for (int kl = 0; kl < 2; ++kl) {
            bf16x8 a0 = *(const bf16x8*)&Ks[buf][kl * 16 + m][quad * 8];
            bf16x8 a1 = *(const bf16x8*)&Ks[buf][kl * 16 + m][32 + quad * 8];
#pragma unroll
            for (int qt = 0; qt < 2; ++qt) {
                f32x4 t = MFMA16(a0, aq[qt][0], zero);
                s[kl][qt] = MFMA16(a1, aq[qt][1], t);
            }
        }

        // p = 2^s; lane holds P[q=lane&15][key=kl*16+quad*4+r]; the f16x8
        // [p_kl0 | p_kl1] is an x32 f16 A-frag under pi(quad*8+j)
        f16x8 p[2];  // [qt]
#pragma unroll
        for (int qt = 0; qt < 2; ++qt)
#pragma unroll
            for (int kl = 0; kl < 2; ++kl) {
                hf2 lo = __builtin_amdgcn_cvt_pkrtz(
                    __builtin_amdgcn_exp2f(s[kl][qt][0]),
                    __builtin_amdgcn_exp2f(s[kl][qt][1]));
                hf2 hi = __builtin_amdgcn_cvt_pkrtz(
                    __builtin_amdgcn_exp2f(s[kl][qt][2]),
                    __builtin_amdgcn_exp2f(s[kl][qt][3]));
                p[qt][kl * 4 + 0] = lo[0]; p[qt][kl * 4 + 1] = lo[1];
                p[qt][kl * 4 + 2] = hi[0]; p[qt][kl * 4 + 3] = hi[1];
            }

        // O[q][f] += P V via x32 f16; B-frag under pi = two b64 reads
#pragma unroll
        for (int ft = 0; ft < 4; ++ft) {
            f16x4 lo = *(const f16x4*)&Vts[buf][ft * 16 + m][quad * 4];
            f16x4 hi = *(const f16x4*)&Vts[buf][ft * 16 + m][16 + quad * 4];
            f16x8 bv;
#pragma unroll
            for (int j = 0; j < 4; ++j) { bv[j] = lo[j]; bv[4 + j] = hi[j]; }
#pragma unroll
            for (int qt = 0; qt < 2; ++qt)
                acc[qt][ft] = MFMA32H(p[qt], bv, acc[qt][ft]);
        }
#pragma unroll
        for (int qt = 0; qt < 2; ++qt)
            acc[qt][4] = MFMA32H(p[qt], ones8, acc[qt][4]);  // row sums

        buf ^= 1;
    }

    // store partials: Op[ks][grow][h*64+f] f16, Ls[ks][grow][h] f32
#pragma unroll
    for (int qt = 0; qt < 2; ++qt)
#pragma unroll
        for (int r = 0; r < 4; ++r) {
            int grow = (b << 11) + q0 + w * 32 + qt * 16 + quad * 4 + r;
            f16_t* op = Op + (((size_t)ks << 12) + grow) * 1024 + (h << 6);
#pragma unroll
            for (int ft = 0; ft < 4; ++ft)
                op[ft * 16 + m] = (f16_t)(acc[qt][ft][r]);
            if (m == 0)
                Ls[((((size_t)ks << 12) + grow) << 4) + h] = acc[qt][4][r];
        }
}

// combine: Os = (Op0 + Op1) / (l0 + l1), bf16 out
__global__ __launch_bounds__(256) void combine(
    const f16_t* __restrict__ Op, const float* __restrict__ Ls,
    bf16_t* __restrict__ Os)
{
    size_t idx = ((size_t)blockIdx.x * 256 + threadIdx.x) * 8;
    int row = (int)(idx >> 10), h = (int)((idx & 1023) >> 6);
    f16x8 a = *(const f16x8*)&Op[idx];
    f16x8 c = *(const f16x8*)&Op[(size_t)4096 * 1024 + idx];
    float l = Ls[row * 16 + h] + Ls[4096 * 16 + row * 16 + h];
    float inv = __builtin_amdgcn_rcpf(l);
    bf16x8 o;
#pragma unroll
    for (int i = 0; i < 8; ++i)
        o[i] = (bf16_t)(((float)a[i] + (float)c[i]) * inv);
    *(bf16x8*)&Os[idx] = o;
}

// ---------------------------------------------------------------------------
extern "C" void kernel_launch(void* const* d_in, const int* in_sizes, int n_in,
                              void* d_out, int out_size, void* d_ws, size_t ws_size,
                              hipStream_t stream)
{
    const float* queries = (const float*)d_in[0];
    const float* keys    = (const float*)d_in[1];
    const float* values  = (const float*)d_in[2];
    const float* Wq = (const float*)d_in[3];
    const float* Wk = (const float*)d_in[4];
    const float* Wv = (const float*)d_in[5];
    const float* bq = (const float*)d_in[6];
    const float* bk = (const float*)d_in[7];
    const float* bv = (const float*)d_in[8];
    const float* Wo = (const float*)d_in[9];
    const float* bo = (const float*)d_in[10];

    char* ws = (char*)d_ws;
    const size_t MB = 1024 * 1024;
    bf16_t* WqT = (bf16_t*)(ws + 0 * MB);   // 2MB each, contiguous (base + z*1M elems)
    bf16_t* WkT = (bf16_t*)(ws + 2 * MB);
    bf16_t* WvT = (bf16_t*)(ws + 4 * MB);
    bf16_t* WoT = (bf16_t*)(ws + 6 * MB);
    bf16_t* qb  = (bf16_t*)(ws + 8 * MB);   // 8MB each: bf16-cast inputs
    bf16_t* kb  = (bf16_t*)(ws + 16 * MB);
    bf16_t* vb  = (bf16_t*)(ws + 24 * MB);
    f16_t*  Vt  = (f16_t*)(ws + 32 * MB);   // 8MB, [b][h*64+f][s] f16
    f16_t*  Op  = (f16_t*)(ws + 40 * MB);   // 16MB, f16 [2][4096][1024] partial O
    float*  Lsp = (float*)(ws + 56 * MB);   // 512KB, f32 [2][4096][16] partial l
    // scratch reuse: Q/K projections live in d_out (16MB) until the final GEMM;
    // combined attention output overwrites qb (no longer needed).
    bf16_t* Qs  = (bf16_t*)d_out;
    bf16_t* Ksb = (bf16_t*)((char*)d_out + 8 * MB);
    bf16_t* Os  = qb;
    (void)WkT; (void)WvT;

    prep<<<4352, 256, 0, stream>>>(Wq, Wk, Wv, Wo, queries, keys, values,
                                   WqT, WkT, WvT, WoT, qb, kb, vb);

    gemm_proj<<<768, 256, 0, stream>>>(qb, kb, vb, WqT, bq, bk, bv,
                                       Qs, Ksb, Vt);

    attn5<<<dim3(32, 16, 2), 256, 0, stream>>>(Qs, Ksb, Vt, Op, Lsp);

    combine<<<2048, 256, 0, stream>>>(Op, Lsp, Os);

    gemm_out<<<512, 256, 0, stream>>>(Os, WoT, bo, (float*)d_out);
}